// Round 5
// baseline (15.245 us; speedup 1.0000x reference)
//
#include <hip/hip_runtime.h>
#include <math.h>

// ---------------------------------------------------------------------------
// Compile-time PGA Cl(3,0,1) tables.
// Blade basis ordering (matches reference):
//   1, e0, e1, e2, e3, e01, e02, e03, e12, e13, e23, e012, e013, e023, e123, e0123
// Bitmask representation: bit0=e0, bit1=e1, bit2=e2, bit3=e3.
// ---------------------------------------------------------------------------
namespace ct {

constexpr int MASK[16] = {0, 1, 2, 4, 8, 3, 5, 9, 6, 10, 12, 7, 11, 13, 14, 15};
constexpr int IDX[16]  = {0, 1, 2, 5, 3, 6, 8, 11, 4, 7, 9, 12, 10, 13, 14, 15};
constexpr int GRADE[16] = {0, 1, 1, 1, 1, 2, 2, 2, 2, 2, 2, 3, 3, 3, 3, 4};

constexpr int popc(int v) { int c = 0; while (v) { c += v & 1; v >>= 1; } return c; }

constexpr int rs(int a, int b) {
    int s = 0;
    a >>= 1;
    while (a) { s += popc(a & b); a >>= 1; }
    return (s & 1) ? -1 : 1;
}

struct Tab { int sgn[16][16]; int idx[16][16]; };

constexpr Tab make_gp() {
    Tab t{};
    for (int i = 0; i < 16; ++i)
        for (int j = 0; j < 16; ++j) {
            int a = MASK[i], b = MASK[j];
            if (a & b & 1) { t.sgn[i][j] = 0; t.idx[i][j] = 0; }
            else           { t.sgn[i][j] = rs(a, b); t.idx[i][j] = IDX[a ^ b]; }
        }
    return t;
}

constexpr Tab make_jn() {
    Tab t{};
    for (int i = 0; i < 16; ++i)
        for (int j = 0; j < 16; ++j) {
            int a = MASK[i], b = MASK[j];
            int ca = 15 ^ a, cb = 15 ^ b;
            if (ca & cb) { t.sgn[i][j] = 0; t.idx[i][j] = 0; }
            else {
                int m = ca | cb;      // wedge in dual space
                int p = 15 ^ m;       // undual
                t.sgn[i][j] = rs(a, ca) * rs(b, cb) * rs(ca, cb) * rs(p, m);
                t.idx[i][j] = IDX[p];
            }
        }
    return t;
}

constexpr Tab GP = make_gp();
constexpr Tab JN = make_jn();

} // namespace ct

// Native vector type accepted by __builtin_nontemporal_load/store
typedef float v4f __attribute__((ext_vector_type(4)));

// ---------------------------------------------------------------------------
// One thread per multivector, direct strided 4x16B access with NON-TEMPORAL
// loads/stores: output never dirties L2 (no per-replay L2 write-back), input
// doesn't churn L2 (read-once per replay; L3 retains it across replays).
// No LDS, no barriers.
// ---------------------------------------------------------------------------
__global__ __launch_bounds__(256) void mvffn_kernel(
    const float* __restrict__ x,
    const float* __restrict__ w1,  const float* __restrict__ v1,  const float* __restrict__ b1,
    const float* __restrict__ w2g, const float* __restrict__ v2g, const float* __restrict__ b2g,
    const float* __restrict__ w2j, const float* __restrict__ v2j, const float* __restrict__ b2j,
    float* __restrict__ out, int n)
{
    const int t = blockIdx.x * blockDim.x + threadIdx.x;
    if (t >= n) return;

    // ---- load one multivector (4 x nontemporal 16B) ----
    const v4f* xv = reinterpret_cast<const v4f*>(x) + (size_t)t * 4;
    v4f q0 = __builtin_nontemporal_load(xv + 0);
    v4f q1 = __builtin_nontemporal_load(xv + 1);
    v4f q2 = __builtin_nontemporal_load(xv + 2);
    v4f q3 = __builtin_nontemporal_load(xv + 3);
    float X[16] = { q0.x, q0.y, q0.z, q0.w,  q1.x, q1.y, q1.z, q1.w,
                    q2.x, q2.y, q2.z, q2.w,  q3.x, q3.y, q3.z, q3.w };

    // ---- uniform parameters (scalar loads) ----
    float W1[5], W2G[5], W2J[5], V1[4], V2G[4], V2J[4];
    #pragma unroll
    for (int i = 0; i < 5; ++i) { W1[i] = w1[i]; W2G[i] = w2g[i]; W2J[i] = w2j[i]; }
    #pragma unroll
    for (int i = 0; i < 4; ++i) { V1[i] = v1[i]; V2G[i] = v2g[i]; V2J[i] = v2j[i]; }
    const float B1 = b1[0], B2G = b2g[0], B2J = b2j[0];

    // ---- MVLinear #1: per-grade scale + e0*x branch + scalar bias ----
    float xp[16];
    #pragma unroll
    for (int k = 0; k < 16; ++k) xp[k] = X[k] * W1[ct::GRADE[k]];
    xp[0]  += B1;
    xp[1]  += V1[1] * X[0];                     // e0   <- 1
    xp[5]  += V1[2] * X[2];                     // e01  <- e1
    xp[6]  += V1[2] * X[3];                     // e02  <- e2
    xp[7]  += V1[2] * X[4];                     // e03  <- e3
    xp[11] += V1[3] * X[8];                     // e012 <- e12
    xp[12] += V1[3] * X[9];                     // e013 <- e13
    xp[13] += V1[3] * X[10];                    // e023 <- e23

    // ---- gated GELU (exact) ----
    const float s0 = xp[0];
    const float gate = 0.5f * s0 * (1.0f + erff(s0 * 0.70710678118654752f));
    float xg[16];
    #pragma unroll
    for (int k = 0; k < 16; ++k) xg[k] = gate * xp[k];

    // ---- bilinear forms: geometric product (192) + join (81) ----
    float gp[16], jn[16];
    #pragma unroll
    for (int k = 0; k < 16; ++k) { gp[k] = 0.0f; jn[k] = 0.0f; }

    #pragma unroll
    for (int i = 0; i < 16; ++i) {
        #pragma unroll
        for (int j = 0; j < 16; ++j) {
            if (ct::GP.sgn[i][j] > 0)      gp[ct::GP.idx[i][j]] += X[i] * xg[j];
            else if (ct::GP.sgn[i][j] < 0) gp[ct::GP.idx[i][j]] -= X[i] * xg[j];
            if (ct::JN.sgn[i][j] > 0)      jn[ct::JN.idx[i][j]] += X[i] * xg[j];
            else if (ct::JN.sgn[i][j] < 0) jn[ct::JN.idx[i][j]] -= X[i] * xg[j];
        }
    }

    // ---- second linears; pseudoscalar gate folded into join weights ----
    const float ps = X[15];
    float psW2J[5], psV2J[4];
    #pragma unroll
    for (int g = 0; g < 5; ++g) psW2J[g] = ps * W2J[g];
    #pragma unroll
    for (int g = 0; g < 4; ++g) psV2J[g] = ps * V2J[g];

    float o[16];
    #pragma unroll
    for (int k = 0; k < 16; ++k)
        o[k] = gp[k] * W2G[ct::GRADE[k]] + jn[k] * psW2J[ct::GRADE[k]];
    o[0]  += B2G + B2J;
    o[1]  += V2G[1] * gp[0]  + psV2J[1] * jn[0];
    o[5]  += V2G[2] * gp[2]  + psV2J[2] * jn[2];
    o[6]  += V2G[2] * gp[3]  + psV2J[2] * jn[3];
    o[7]  += V2G[2] * gp[4]  + psV2J[2] * jn[4];
    o[11] += V2G[3] * gp[8]  + psV2J[3] * jn[8];
    o[12] += V2G[3] * gp[9]  + psV2J[3] * jn[9];
    o[13] += V2G[3] * gp[10] + psV2J[3] * jn[10];

    // ---- store (4 x nontemporal 16B) ----
    v4f* ov = reinterpret_cast<v4f*>(out) + (size_t)t * 4;
    v4f r0 = { o[0],  o[1],  o[2],  o[3]  };
    v4f r1 = { o[4],  o[5],  o[6],  o[7]  };
    v4f r2 = { o[8],  o[9],  o[10], o[11] };
    v4f r3 = { o[12], o[13], o[14], o[15] };
    __builtin_nontemporal_store(r0, ov + 0);
    __builtin_nontemporal_store(r1, ov + 1);
    __builtin_nontemporal_store(r2, ov + 2);
    __builtin_nontemporal_store(r3, ov + 3);
}

extern "C" void kernel_launch(void* const* d_in, const int* in_sizes, int n_in,
                              void* d_out, int out_size, void* d_ws, size_t ws_size,
                              hipStream_t stream) {
    const float* x   = (const float*)d_in[0];
    const float* w1  = (const float*)d_in[1];
    const float* v1  = (const float*)d_in[2];
    const float* b1  = (const float*)d_in[3];
    const float* w2g = (const float*)d_in[4];
    const float* v2g = (const float*)d_in[5];
    const float* b2g = (const float*)d_in[6];
    const float* w2j = (const float*)d_in[7];
    const float* v2j = (const float*)d_in[8];
    const float* b2j = (const float*)d_in[9];
    float* out = (float*)d_out;

    const int n = in_sizes[0] / 16;          // number of multivectors
    const int block = 256;
    const int grid = (n + block - 1) / block;
    mvffn_kernel<<<grid, block, 0, stream>>>(x, w1, v1, b1, w2g, v2g, b2g,
                                             w2j, v2j, b2j, out, n);
}